// Round 7
// baseline (223.092 us; speedup 1.0000x reference)
//
#include <hip/hip_runtime.h>
#include <math.h>

typedef _Float16 half8 __attribute__((ext_vector_type(8)));
typedef _Float16 half2h __attribute__((ext_vector_type(2)));
typedef float floatx4 __attribute__((ext_vector_type(4)));

#define HDIM 256
#define NC 15        // value + 4 grad + 10 hess (00,01,02,03,11,12,13,22,23,33)
#define SPB 16       // samples per block
#define KH 128       // K streamed in two halves
#define STRIDE 136   // f16 per LDS row: 128 + 8 pad
#define MROWS 240    // 15 comps * 16 samples
#define NWAVE 4
#define NT 4         // n-tiles per wave

// ---------------------------------------------------------------------------
// Per-sample analytic Einstein tensor from (f, grad f, hess f). One lane.
// ---------------------------------------------------------------------------
__device__ __forceinline__ void einstein_tail(
    float f, const float* Gf, const float* Hs, float r, float th,
    float* __restrict__ outp)
{
    float Hf[4][4];
    {
        int qq = 0;
#pragma unroll
        for (int k = 0; k < 4; ++k)
#pragma unroll
            for (int l = k; l < 4; ++l) { Hf[k][l] = Hs[qq]; Hf[l][k] = Hs[qq]; ++qq; }
    }
    float sn = sinf(th), cs = cosf(th);
    float E  = expf(f);

    float gd[4] = {-1.f, E, r * r, r * r * sn * sn};
    float gi[4];
#pragma unroll
    for (int a = 0; a < 4; ++a) gi[a] = 1.f / gd[a];

    float dgv[4][4];
    float ddg[4][4][4];
#pragma unroll
    for (int a = 0; a < 4; ++a)
#pragma unroll
        for (int k = 0; k < 4; ++k) {
            dgv[a][k] = 0.f;
#pragma unroll
            for (int l = 0; l < 4; ++l) ddg[a][k][l] = 0.f;
        }
#pragma unroll
    for (int k = 0; k < 4; ++k) dgv[1][k] = E * Gf[k];
    dgv[2][1] = 2.f * r;
    dgv[3][1] = 2.f * r * sn * sn;
    dgv[3][2] = 2.f * r * r * sn * cs;
#pragma unroll
    for (int k = 0; k < 4; ++k)
#pragma unroll
        for (int l = 0; l < 4; ++l)
            ddg[1][k][l] = E * fmaf(Gf[k], Gf[l], Hf[k][l]);
    ddg[2][1][1] = 2.f;
    ddg[3][1][1] = 2.f * sn * sn;
    ddg[3][1][2] = 4.f * r * sn * cs;
    ddg[3][2][1] = 4.f * r * sn * cs;
    ddg[3][2][2] = 2.f * r * r * (cs * cs - sn * sn);

    auto SYMF = [&](int a, int i, int jx) -> float {
        float sy = 0.f;
        if (a == i)  sy += dgv[a][jx];
        if (a == jx) sy += dgv[a][i];
        if (i == jx) sy -= dgv[i][a];
        return sy;
    };
    auto DF = [&](int a, int i, int jx, int k) -> float {
        float ds = 0.f;
        if (a == i)  ds += ddg[a][jx][k];
        if (a == jx) ds += ddg[a][i][k];
        if (i == jx) ds -= ddg[i][a][k];
        return 0.5f * (gi[a] * ds - gi[a] * gi[a] * dgv[a][k] * SYMF(a, i, jx));
    };

    float Gm[4][4][4];
#pragma unroll
    for (int a = 0; a < 4; ++a)
#pragma unroll
        for (int i = 0; i < 4; ++i)
#pragma unroll
            for (int jx = 0; jx < 4; ++jx)
                Gm[a][i][jx] = 0.5f * gi[a] * SYMF(a, i, jx);

    float ric[4][4];
#pragma unroll
    for (int b = 0; b < 4; ++b)
#pragma unroll
        for (int d = 0; d < 4; ++d) {
            float sum = 0.f;
#pragma unroll
            for (int a = 0; a < 4; ++a) {
                sum += DF(a, d, b, a) - DF(a, a, b, d);
#pragma unroll
                for (int e = 0; e < 4; ++e)
                    sum += Gm[a][a][e] * Gm[e][d][b] - Gm[a][d][e] * Gm[e][a][b];
            }
            ric[b][d] = sum;
        }

    float Rs = 0.f;
#pragma unroll
    for (int b = 0; b < 4; ++b) Rs += gi[b] * ric[b][b];

#pragma unroll
    for (int a = 0; a < 4; ++a)
#pragma unroll
        for (int b = 0; b < 4; ++b) {
            float v = gi[a] * gi[b] * ric[a][b];
            if (a == b) v -= 0.5f * gi[a] * Rs;
            outp[a * 4 + b] = v;
        }
}

// ---------------------------------------------------------------------------
// Coalesced 64x64 LDS-tile transpose: Wt[m][j*256+k] = (f16)W_m[k*256+j].
// ---------------------------------------------------------------------------
__global__ __launch_bounds__(256) void pack_wt(
    const float* __restrict__ W2, const float* __restrict__ W3,
    _Float16* __restrict__ Wt)
{
    __shared__ float t[64][65];
    const int m    = blockIdx.x >> 4;
    const float* W = m ? W3 : W2;
    const int tile = blockIdx.x & 15;
    const int k0 = (tile >> 2) * 64, j0 = (tile & 3) * 64;
    const int tx = threadIdx.x & 63, ty = threadIdx.x >> 6;   // 64 x 4
#pragma unroll
    for (int i = 0; i < 16; ++i) {
        int k = ty + i * 4;
        t[k][tx] = W[(k0 + k) * HDIM + j0 + tx];              // coalesced read
    }
    __syncthreads();
#pragma unroll
    for (int i = 0; i < 16; ++i) {
        int jj = ty + i * 4;
        Wt[(size_t)m * HDIM * HDIM + (j0 + jj) * HDIM + k0 + tx] =
            (_Float16)t[tx][jj];                              // coalesced write
    }
}

// ---------------------------------------------------------------------------
// Fused kernel: MFMA forward-mode (value,grad,hess) + Einstein tail.
// Block = 256 thr (4 waves, ONE wave per SIMD -> up to 512 unified regs/wave:
// the R6 lesson — at 2 waves/SIMD the 256-reg budget forced ~65 B/thread of
// scratch spill; acc[15][4]=240 + hold(120) + frags fits only at 1 wave/SIMD).
// 16 samples/block. M=240 (m=c*16+sl), N=256, K=256 per layer, K streamed in
// halves through one 65,280B LDS buffer. Wave w owns 4 n-tiles (64 neurons);
// each A-frag ds_read feeds 4 MFMAs. Latency hiding is ILP (60 independent
// MFMAs per k-step), not occupancy.
// ---------------------------------------------------------------------------
template <bool TW>
__global__ __launch_bounds__(256, 1) void mlp_fused(
    const float* __restrict__ coords,
    const float* __restrict__ W1, const float* __restrict__ b1,
    const float* __restrict__ W2, const float* __restrict__ b2,
    const float* __restrict__ W3, const float* __restrict__ b3,
    const float* __restrict__ Wo, const float* __restrict__ bo,
    const _Float16* __restrict__ Wt,   // packed f16 W2^T | W3^T (TW only)
    float* __restrict__ out, int B)
{
    __shared__ __align__(16) _Float16 st[MROWS * STRIDE];   // 65,280 B

    const int tid  = threadIdx.x;
    const int w    = tid >> 6;       // wave 0..3
    const int lane = tid & 63;
    const int col  = lane & 15;
    const int q    = lane >> 4;
    const int s0   = blockIdx.x * SPB;

    floatx4 acc[NC][NT];             // 240 regs
    _Float16 hold[NC * NT * 4];      // 120 regs, transient (c*16 + nt*4 + r)

    // ---- layer-1 producer: 16 thr/sample, 8 cols/thread in 2-col passes ----
    auto produce1 = [&](int half) {
        const int sl = tid & 15;
        const int cp = tid >> 4;                 // 0..15
        int ss = s0 + sl; if (ss >= B) ss = B - 1;
        const float x0 = coords[ss * 4 + 0];
        const float x1 = coords[ss * 4 + 1];
        const float x2 = coords[ss * 4 + 2];
        const float x3 = coords[ss * 4 + 3];
#pragma unroll
        for (int pass = 0; pass < 4; ++pass) {
            const int jl0 = cp * 8 + pass * 2;
            const int jg  = half * KH + jl0;
            float2 wr0 = *(const float2*)&W1[0 * HDIM + jg];
            float2 wr1 = *(const float2*)&W1[1 * HDIM + jg];
            float2 wr2 = *(const float2*)&W1[2 * HDIM + jg];
            float2 wr3 = *(const float2*)&W1[3 * HDIM + jg];
            float2 bb  = *(const float2*)&b1[jg];
            float o2[2][NC];                     // constant-indexed -> regs
#pragma unroll
            for (int t = 0; t < 2; ++t) {
                float w0 = t ? wr0.y : wr0.x, w1 = t ? wr1.y : wr1.x;
                float w2v = t ? wr2.y : wr2.x, w3v = t ? wr3.y : wr3.x;
                float a = t ? bb.y : bb.x;
                a = fmaf(x0, w0, a); a = fmaf(x1, w1, a);
                a = fmaf(x2, w2v, a); a = fmaf(x3, w3v, a);
                float v = tanhf(a), tp = 1.f - v * v, m2 = -2.f * v * tp;
                float g[4] = {w0, w1, w2v, w3v};
                o2[t][0] = v;
                o2[t][1] = tp * w0; o2[t][2] = tp * w1;
                o2[t][3] = tp * w2v; o2[t][4] = tp * w3v;
                int idx = 5;
#pragma unroll
                for (int aa = 0; aa < 4; ++aa)
#pragma unroll
                    for (int bb2 = aa; bb2 < 4; ++bb2) {
                        o2[t][idx] = m2 * g[aa] * g[bb2]; ++idx;
                    }
            }
#pragma unroll
            for (int c = 0; c < NC; ++c) {
                half2h pk; pk[0] = (_Float16)o2[0][c]; pk[1] = (_Float16)o2[1][c];
                *(half2h*)&st[(c * 16 + sl) * STRIDE + jl0] = pk;
            }
        }
    };

    auto init_acc = [&](const float* __restrict__ b) {
#pragma unroll
        for (int nt = 0; nt < NT; ++nt) {
            float bj = b[w * 64 + nt * 16 + col];
#pragma unroll
            for (int c = 0; c < NC; ++c)
#pragma unroll
                for (int r = 0; r < 4; ++r) acc[c][nt][r] = 0.f;
#pragma unroll
            for (int r = 0; r < 4; ++r) acc[0][nt][r] = bj;
        }
    };

    // GEMM over one K-half: A = st (f16 LDS), B = W rows [half*128, +128)
    auto gemm_half = [&](const float* __restrict__ W, int layer, int half) {
#pragma unroll
        for (int ks = 0; ks < 4; ++ks) {
            const int kg = half * KH + ks * 32 + q * 8;
            half8 bf[NT];
#pragma unroll
            for (int nt = 0; nt < NT; ++nt) {
                const int j = w * 64 + nt * 16 + col;
                if constexpr (TW) {
                    bf[nt] = *(const half8*)&Wt[((size_t)layer * HDIM + j) * HDIM + kg];
                } else {
#pragma unroll
                    for (int i = 0; i < 8; ++i)
                        bf[nt][i] = (_Float16)W[(kg + i) * HDIM + j];
                }
            }
#pragma unroll
            for (int mt = 0; mt < NC; ++mt) {
                half8 af = *(const half8*)&st[(mt * 16 + col) * STRIDE + ks * 32 + q * 8];
#pragma unroll
                for (int nt = 0; nt < NT; ++nt)
                    acc[mt][nt] = __builtin_amdgcn_mfma_f32_16x16x32_f16(
                        af, bf[nt], acc[mt][nt], 0, 0, 0);
            }
        }
    };

    // tanh chain rule on acc -> hold (f16)
    auto transform_hold = [&]() {
#pragma unroll
        for (int nt = 0; nt < NT; ++nt)
#pragma unroll
            for (int r = 0; r < 4; ++r) {
                float pre[NC];
#pragma unroll
                for (int c = 0; c < NC; ++c) pre[c] = acc[c][nt][r];
                float v = tanhf(pre[0]), tp = 1.f - v * v, m2 = -2.f * v * tp;
                float g[4] = {pre[1], pre[2], pre[3], pre[4]};
                hold[0 * 16 + nt * 4 + r] = (_Float16)v;
#pragma unroll
                for (int k = 0; k < 4; ++k)
                    hold[(1 + k) * 16 + nt * 4 + r] = (_Float16)(tp * g[k]);
                int idx = 5;
#pragma unroll
                for (int aa = 0; aa < 4; ++aa)
#pragma unroll
                    for (int bb2 = aa; bb2 < 4; ++bb2) {
                        hold[idx * 16 + nt * 4 + r] =
                            (_Float16)fmaf(tp, pre[idx], m2 * g[aa] * g[bb2]);
                        ++idx;
                    }
            }
    };

    auto store_hold = [&](int half) {
#pragma unroll
        for (int nt = 0; nt < NT; ++nt) {
            const int jl = w * 64 + nt * 16 + col - half * KH;   // in [0,128)
#pragma unroll
            for (int c = 0; c < NC; ++c)
#pragma unroll
                for (int r = 0; r < 4; ++r)
                    st[(c * 16 + q * 4 + r) * STRIDE + jl] = hold[c * 16 + nt * 4 + r];
        }
    };

    // ================= pipeline =================
    produce1(0);
    __syncthreads();
    init_acc(b2);
    gemm_half(W2, 0, 0);
    __syncthreads();
    produce1(1);
    __syncthreads();
    gemm_half(W2, 0, 1);
    __syncthreads();                  // layer-1 state fully consumed
    transform_hold();                 // layer-2 state (f16, regs)
    if (w < 2) store_hold(0);         // waves owning j<128
    __syncthreads();
    init_acc(b3);
    gemm_half(W3, 1, 0);
    __syncthreads();
    if (w >= 2) store_hold(1);
    __syncthreads();
    gemm_half(W3, 1, 1);

    // ---- epilogue: layer-3 tanh chain + Wo dot, streamed per row r ----
    __syncthreads();                  // all st (A-frag) reads done; alias ok
    float* part = (float*)st;         // [0, 960): part[w][c][sl]
    float* fin  = ((float*)st) + 4096;// [4096, 4352): fin[sl][c]
    float wo[NT];
#pragma unroll
    for (int nt = 0; nt < NT; ++nt) wo[nt] = Wo[w * 64 + nt * 16 + col];
#pragma unroll
    for (int r = 0; r < 4; ++r) {
        float on[NC];
#pragma unroll
        for (int c = 0; c < NC; ++c) on[c] = 0.f;
#pragma unroll
        for (int nt = 0; nt < NT; ++nt) {
            float pre[NC];
#pragma unroll
            for (int c = 0; c < NC; ++c) pre[c] = acc[c][nt][r];
            float v = tanhf(pre[0]), tp = 1.f - v * v, m2 = -2.f * v * tp;
            float g0 = pre[1], g1 = pre[2], g2 = pre[3], g3 = pre[4];
            on[0] = fmaf(wo[nt], v, on[0]);
            on[1] = fmaf(wo[nt], tp * g0, on[1]);
            on[2] = fmaf(wo[nt], tp * g1, on[2]);
            on[3] = fmaf(wo[nt], tp * g2, on[3]);
            on[4] = fmaf(wo[nt], tp * g3, on[4]);
            float gg[4] = {g0, g1, g2, g3};
            int idx = 5;
#pragma unroll
            for (int aa = 0; aa < 4; ++aa)
#pragma unroll
                for (int bb2 = aa; bb2 < 4; ++bb2) {
                    on[idx] = fmaf(wo[nt], fmaf(tp, pre[idx], m2 * gg[aa] * gg[bb2]),
                                   on[idx]);
                    ++idx;
                }
        }
#pragma unroll
        for (int mask = 1; mask < 16; mask <<= 1)
#pragma unroll
            for (int c = 0; c < NC; ++c)
                on[c] += __shfl_xor(on[c], mask, 64);
        if (col == 0) {
#pragma unroll
            for (int c = 0; c < NC; ++c)
                part[w * MROWS + c * 16 + q * 4 + r] = on[c];
        }
    }
    __syncthreads();
    if (tid < MROWS) {
        float v = 0.f;
#pragma unroll
        for (int ww = 0; ww < NWAVE; ++ww) v += part[ww * MROWS + tid];
        int c = tid >> 4, sl = tid & 15;
        if (c == 0) v += bo[0];
        fin[sl * 16 + c] = v;
    }
    __syncthreads();
    if (tid < SPB) {
        int s = s0 + tid;
        if (s < B) {
            float f = fin[tid * 16 + 0];
            float Gf[4], Hs[10];
#pragma unroll
            for (int k = 0; k < 4; ++k) Gf[k] = fin[tid * 16 + 1 + k];
#pragma unroll
            for (int qq = 0; qq < 10; ++qq) Hs[qq] = fin[tid * 16 + 5 + qq];
            float r  = coords[s * 4 + 1];
            float th = coords[s * 4 + 2];
            float res[16];
            einstein_tail(f, Gf, Hs, r, th, res);
#pragma unroll
            for (int e = 0; e < 16; ++e) out[s * 16 + e] = res[e];
        }
    }
}

extern "C" void kernel_launch(void* const* d_in, const int* in_sizes, int n_in,
                              void* d_out, int out_size, void* d_ws, size_t ws_size,
                              hipStream_t stream) {
    const float* coords = (const float*)d_in[0];
    const float* W1 = (const float*)d_in[1];
    const float* b1 = (const float*)d_in[2];
    const float* W2 = (const float*)d_in[3];
    const float* b2 = (const float*)d_in[4];
    const float* W3 = (const float*)d_in[5];
    const float* b3 = (const float*)d_in[6];
    const float* Wo = (const float*)d_in[7];
    const float* bo = (const float*)d_in[8];
    float* out = (float*)d_out;
    const int B = in_sizes[0] / 4;
    const int nblocks = (B + SPB - 1) / SPB;

    const size_t wt_bytes = (size_t)2 * HDIM * HDIM * sizeof(_Float16);
    if (ws_size >= wt_bytes) {
        _Float16* Wt = (_Float16*)d_ws;
        pack_wt<<<32, 256, 0, stream>>>(W2, W3, Wt);
        mlp_fused<true><<<nblocks, 256, 0, stream>>>(
            coords, W1, b1, W2, b2, W3, b3, Wo, bo, Wt, out, B);
    } else {
        mlp_fused<false><<<nblocks, 256, 0, stream>>>(
            coords, W1, b1, W2, b2, W3, b3, Wo, bo, nullptr, out, B);
    }
}

// Round 8
// 131.838 us; speedup vs baseline: 1.6922x; 1.6922x over previous
//
#include <hip/hip_runtime.h>
#include <math.h>

typedef _Float16 half8 __attribute__((ext_vector_type(8)));
typedef float floatx4 __attribute__((ext_vector_type(4)));

#define HDIM 256
#define NC 15        // value + 4 grad + 10 hess
#define NCP 16       // comps padded to 16 (comp 15 = always zero)
#define SPB 8        // samples per block
#define MR 128       // M rows = NCP * SPB
#define NWAVE 4
#define NT 4         // n-tiles per wave (64 neurons)

// Row mapping: m = 16*(c>>1) + 4*(sl>>1) + 2*(sl&1) + (c&1).
// => MFMA C/D lane (col, q) rows m=16mt+4q+r hold comp c=2mt+(r&1) of sample
//    sl=2q+(r>>1): every lane owns ALL 16 comps of 2 samples -> chain rule is
//    register-local, no cross-lane exchange, no hold-across-GEMM.
// LDS: st[128][256] f16 = 65536 B exactly; chunk-of-8-f16 XOR swizzle
//    phys_chunk = logical_chunk ^ (m & 31)  (banks spread, b128-friendly).

// ---------------------------------------------------------------------------
// Per-sample analytic Einstein tensor from (f, grad f, hess f). One lane.
// ---------------------------------------------------------------------------
__device__ __forceinline__ void einstein_tail(
    float f, const float* Gf, const float* Hs, float r, float th,
    float* __restrict__ outp)
{
    float Hf[4][4];
    {
        int qq = 0;
#pragma unroll
        for (int k = 0; k < 4; ++k)
#pragma unroll
            for (int l = k; l < 4; ++l) { Hf[k][l] = Hs[qq]; Hf[l][k] = Hs[qq]; ++qq; }
    }
    float sn = sinf(th), cs = cosf(th);
    float E  = expf(f);

    float gd[4] = {-1.f, E, r * r, r * r * sn * sn};
    float gi[4];
#pragma unroll
    for (int a = 0; a < 4; ++a) gi[a] = 1.f / gd[a];

    float dgv[4][4];
    float ddg[4][4][4];
#pragma unroll
    for (int a = 0; a < 4; ++a)
#pragma unroll
        for (int k = 0; k < 4; ++k) {
            dgv[a][k] = 0.f;
#pragma unroll
            for (int l = 0; l < 4; ++l) ddg[a][k][l] = 0.f;
        }
#pragma unroll
    for (int k = 0; k < 4; ++k) dgv[1][k] = E * Gf[k];
    dgv[2][1] = 2.f * r;
    dgv[3][1] = 2.f * r * sn * sn;
    dgv[3][2] = 2.f * r * r * sn * cs;
#pragma unroll
    for (int k = 0; k < 4; ++k)
#pragma unroll
        for (int l = 0; l < 4; ++l)
            ddg[1][k][l] = E * fmaf(Gf[k], Gf[l], Hf[k][l]);
    ddg[2][1][1] = 2.f;
    ddg[3][1][1] = 2.f * sn * sn;
    ddg[3][1][2] = 4.f * r * sn * cs;
    ddg[3][2][1] = 4.f * r * sn * cs;
    ddg[3][2][2] = 2.f * r * r * (cs * cs - sn * sn);

    auto SYMF = [&](int a, int i, int jx) -> float {
        float sy = 0.f;
        if (a == i)  sy += dgv[a][jx];
        if (a == jx) sy += dgv[a][i];
        if (i == jx) sy -= dgv[i][a];
        return sy;
    };
    auto DF = [&](int a, int i, int jx, int k) -> float {
        float ds = 0.f;
        if (a == i)  ds += ddg[a][jx][k];
        if (a == jx) ds += ddg[a][i][k];
        if (i == jx) ds -= ddg[i][a][k];
        return 0.5f * (gi[a] * ds - gi[a] * gi[a] * dgv[a][k] * SYMF(a, i, jx));
    };

    float Gm[4][4][4];
#pragma unroll
    for (int a = 0; a < 4; ++a)
#pragma unroll
        for (int i = 0; i < 4; ++i)
#pragma unroll
            for (int jx = 0; jx < 4; ++jx)
                Gm[a][i][jx] = 0.5f * gi[a] * SYMF(a, i, jx);

    float ric[4][4];
#pragma unroll
    for (int b = 0; b < 4; ++b)
#pragma unroll
        for (int d = 0; d < 4; ++d) {
            float sum = 0.f;
#pragma unroll
            for (int a = 0; a < 4; ++a) {
                sum += DF(a, d, b, a) - DF(a, a, b, d);
#pragma unroll
                for (int e = 0; e < 4; ++e)
                    sum += Gm[a][a][e] * Gm[e][d][b] - Gm[a][d][e] * Gm[e][a][b];
            }
            ric[b][d] = sum;
        }

    float Rs = 0.f;
#pragma unroll
    for (int b = 0; b < 4; ++b) Rs += gi[b] * ric[b][b];

#pragma unroll
    for (int a = 0; a < 4; ++a)
#pragma unroll
        for (int b = 0; b < 4; ++b) {
            float v = gi[a] * gi[b] * ric[a][b];
            if (a == b) v -= 0.5f * gi[a] * Rs;
            outp[a * 4 + b] = v;
        }
}

// ---------------------------------------------------------------------------
// Coalesced 64x64 LDS-tile transpose: Wt[m][j*256+k] = (f16)W_m[k*256+j].
// ---------------------------------------------------------------------------
__global__ __launch_bounds__(256) void pack_wt(
    const float* __restrict__ W2, const float* __restrict__ W3,
    _Float16* __restrict__ Wt)
{
    __shared__ float t[64][65];
    const int m    = blockIdx.x >> 4;
    const float* W = m ? W3 : W2;
    const int tile = blockIdx.x & 15;
    const int k0 = (tile >> 2) * 64, j0 = (tile & 3) * 64;
    const int tx = threadIdx.x & 63, ty = threadIdx.x >> 6;   // 64 x 4
#pragma unroll
    for (int i = 0; i < 16; ++i) {
        int k = ty + i * 4;
        t[k][tx] = W[(k0 + k) * HDIM + j0 + tx];              // coalesced read
    }
    __syncthreads();
#pragma unroll
    for (int i = 0; i < 16; ++i) {
        int jj = ty + i * 4;
        Wt[(size_t)m * HDIM * HDIM + (j0 + jj) * HDIM + k0 + tx] =
            (_Float16)t[tx][jj];                              // coalesced write
    }
}

// ---------------------------------------------------------------------------
// Fused kernel. Block = 256 thr (4 waves), 8 samples, __launch_bounds__(256,2)
// -> <=256 regs/wave, 2 blocks/CU (LDS 64KB). acc[8][4] = 128 unified regs;
// peak live ~190 -> no spill (the R3-R7 lesson: any design holding layer
// state in regs ACROSS a GEMM spills; here transform->store is immediate
// because the whole K=256 state fits one LDS buffer).
// ---------------------------------------------------------------------------
template <bool TW>
__global__ __launch_bounds__(256, 2) void mlp_fused(
    const float* __restrict__ coords,
    const float* __restrict__ W1, const float* __restrict__ b1,
    const float* __restrict__ W2, const float* __restrict__ b2,
    const float* __restrict__ W3, const float* __restrict__ b3,
    const float* __restrict__ Wo, const float* __restrict__ bo,
    const _Float16* __restrict__ Wt,   // packed f16 W2^T | W3^T (TW only)
    float* __restrict__ out, int B)
{
    __shared__ __align__(16) _Float16 st[MR * HDIM];   // 65,536 B exactly

    const int tid  = threadIdx.x;
    const int w    = tid >> 6;       // wave 0..3
    const int lane = tid & 63;
    const int col  = lane & 15;
    const int q    = lane >> 4;
    const int s0   = blockIdx.x * SPB;

    floatx4 acc[8][NT];              // 128 unified regs

    auto f4get = [](const float4& v, int i) -> float {
        switch (i & 3) { case 0: return v.x; case 1: return v.y;
                         case 2: return v.z; default: return v.w; }
    };

    // ---- layer-1 producer: thread = (sample sl, chunk t of 8 cols) ----
    auto produce1 = [&]() {
        const int sl = tid & 7;
        const int tc = tid >> 3;               // 0..31
        int ss = s0 + sl; if (ss >= B) ss = B - 1;
        const float x0 = coords[ss * 4 + 0];
        const float x1 = coords[ss * 4 + 1];
        const float x2 = coords[ss * 4 + 2];
        const float x3 = coords[ss * 4 + 3];
        const int jg = tc * 8;
        float4 wa[4][2];
#pragma unroll
        for (int k = 0; k < 4; ++k) {
            wa[k][0] = *(const float4*)&W1[k * HDIM + jg];
            wa[k][1] = *(const float4*)&W1[k * HDIM + jg + 4];
        }
        float4 bb0 = *(const float4*)&b1[jg];
        float4 bb1 = *(const float4*)&b1[jg + 4];
        half8 ch[NCP];
#pragma unroll
        for (int jj = 0; jj < 8; ++jj) ch[15][jj] = (_Float16)0.f;
#pragma unroll
        for (int jj = 0; jj < 8; ++jj) {
            const int h = jj >> 2;
            float w0 = f4get(wa[0][h], jj), w1 = f4get(wa[1][h], jj);
            float w2v = f4get(wa[2][h], jj), w3v = f4get(wa[3][h], jj);
            float a = f4get(h ? bb1 : bb0, jj);
            a = fmaf(x0, w0, a); a = fmaf(x1, w1, a);
            a = fmaf(x2, w2v, a); a = fmaf(x3, w3v, a);
            float v = tanhf(a), tp = 1.f - v * v, m2 = -2.f * v * tp;
            float g[4] = {w0, w1, w2v, w3v};
            ch[0][jj] = (_Float16)v;
#pragma unroll
            for (int k = 0; k < 4; ++k) ch[1 + k][jj] = (_Float16)(tp * g[k]);
            int idx = 5;
#pragma unroll
            for (int aa = 0; aa < 4; ++aa)
#pragma unroll
                for (int bb2 = aa; bb2 < 4; ++bb2) {
                    ch[idx][jj] = (_Float16)(m2 * g[aa] * g[bb2]); ++idx;
                }
        }
#pragma unroll
        for (int c = 0; c < NCP; ++c) {
            const int m = 16 * (c >> 1) + 4 * (sl >> 1) + 2 * (sl & 1) + (c & 1);
            const int addr = m * HDIM + (((tc ^ m) & 31) << 3);
            *(half8*)&st[addr] = ch[c];
        }
    };

    auto init_acc = [&](const float* __restrict__ b) {
#pragma unroll
        for (int nt = 0; nt < NT; ++nt) {
            float bj = b[w * 64 + nt * 16 + col];
#pragma unroll
            for (int mt = 0; mt < 8; ++mt)
#pragma unroll
                for (int r = 0; r < 4; ++r) acc[mt][nt][r] = 0.f;
            acc[0][nt][0] = bj;    // comp 0, sample-local 0
            acc[0][nt][2] = bj;    // comp 0, sample-local 1
        }
    };

    // full-K GEMM: A = st (swizzled LDS), B = Wt rows (f16, k-contiguous)
    auto gemm_full = [&](const float* __restrict__ W, int layer) {
#pragma unroll
        for (int ks = 0; ks < 8; ++ks) {
            const int kg = ks * 32 + q * 8;
            half8 bf[NT];
#pragma unroll
            for (int nt = 0; nt < NT; ++nt) {
                const int j = w * 64 + nt * 16 + col;
                if constexpr (TW) {
                    bf[nt] = *(const half8*)&Wt[((size_t)layer * HDIM + j) * HDIM + kg];
                } else {
#pragma unroll
                    for (int i = 0; i < 8; ++i)
                        bf[nt][i] = (_Float16)W[(kg + i) * HDIM + j];
                }
            }
            const int lc = ks * 4 + q;         // logical chunk
#pragma unroll
            for (int mt = 0; mt < 8; ++mt) {
                const int m = 16 * mt + col;
                half8 af = *(const half8*)&st[m * HDIM + (((lc ^ m) & 31) << 3)];
#pragma unroll
                for (int nt = 0; nt < NT; ++nt)
                    acc[mt][nt] = __builtin_amdgcn_mfma_f32_16x16x32_f16(
                        af, bf[nt], acc[mt][nt], 0, 0, 0);
            }
        }
    };

    // tanh chain rule + immediate LDS store (register-local, no hold)
    auto transform_store = [&]() {
#pragma unroll
        for (int nt = 0; nt < NT; ++nt) {
            const int j = w * 64 + nt * 16 + col;
            const int jc = j >> 3, jb = j & 7;
#pragma unroll
            for (int sv = 0; sv < 2; ++sv) {           // sample-local
                float pre[NCP];
#pragma unroll
                for (int c = 0; c < NCP; ++c)
                    pre[c] = acc[c >> 1][nt][sv * 2 + (c & 1)];
                float v = tanhf(pre[0]), tp = 1.f - v * v, m2 = -2.f * v * tp;
                float g[4] = {pre[1], pre[2], pre[3], pre[4]};
                float ns[NCP];
                ns[0] = v;
#pragma unroll
                for (int k = 0; k < 4; ++k) ns[1 + k] = tp * g[k];
                int idx = 5;
#pragma unroll
                for (int aa = 0; aa < 4; ++aa)
#pragma unroll
                    for (int bb2 = aa; bb2 < 4; ++bb2) {
                        ns[idx] = fmaf(tp, pre[idx], m2 * g[aa] * g[bb2]); ++idx;
                    }
                ns[15] = 0.f;
#pragma unroll
                for (int c = 0; c < NCP; ++c) {
                    const int m = 16 * (c >> 1) + 4 * q + 2 * sv + (c & 1);
                    st[m * HDIM + (((jc ^ m) & 31) << 3) + jb] = (_Float16)ns[c];
                }
            }
        }
    };

    // ================= pipeline =================
    produce1();
    __syncthreads();
    init_acc(b2);
    gemm_full(W2, 0);
    __syncthreads();                  // layer-1 state consumed
    transform_store();                // layer-2 state -> st (immediate)
    __syncthreads();
    init_acc(b3);
    gemm_full(W3, 1);

    // ---- epilogue: layer-3 tanh chain + Wo dot ----
    __syncthreads();                  // st consumed; alias for partials
    float* part = (float*)st;         // [0, 480): part[w][sl][c]
    float* fin  = ((float*)st) + 512; // [512, 640): fin[sl][16]
    float wo[NT];
#pragma unroll
    for (int nt = 0; nt < NT; ++nt) wo[nt] = Wo[w * 64 + nt * 16 + col];

    float on2[2][NC];
#pragma unroll
    for (int sv = 0; sv < 2; ++sv)
#pragma unroll
        for (int c = 0; c < NC; ++c) on2[sv][c] = 0.f;
#pragma unroll
    for (int nt = 0; nt < NT; ++nt)
#pragma unroll
        for (int sv = 0; sv < 2; ++sv) {
            float pre[NCP];
#pragma unroll
            for (int c = 0; c < NCP; ++c)
                pre[c] = acc[c >> 1][nt][sv * 2 + (c & 1)];
            float v = tanhf(pre[0]), tp = 1.f - v * v, m2 = -2.f * v * tp;
            float g[4] = {pre[1], pre[2], pre[3], pre[4]};
            on2[sv][0] = fmaf(wo[nt], v, on2[sv][0]);
#pragma unroll
            for (int k = 0; k < 4; ++k)
                on2[sv][1 + k] = fmaf(wo[nt], tp * g[k], on2[sv][1 + k]);
            int idx = 5;
#pragma unroll
            for (int aa = 0; aa < 4; ++aa)
#pragma unroll
                for (int bb2 = aa; bb2 < 4; ++bb2) {
                    on2[sv][idx] = fmaf(wo[nt],
                        fmaf(tp, pre[idx], m2 * g[aa] * g[bb2]), on2[sv][idx]);
                    ++idx;
                }
        }
#pragma unroll
    for (int mask = 1; mask < 16; mask <<= 1)
#pragma unroll
        for (int sv = 0; sv < 2; ++sv)
#pragma unroll
            for (int c = 0; c < NC; ++c)
                on2[sv][c] += __shfl_xor(on2[sv][c], mask, 64);
    if (col == 0) {
#pragma unroll
        for (int sv = 0; sv < 2; ++sv)
#pragma unroll
            for (int c = 0; c < NC; ++c)
                part[(w * SPB + 2 * q + sv) * NC + c] = on2[sv][c];
    }
    __syncthreads();
    if (tid < SPB * NC) {             // 120 threads
        const int sl = tid / NC, c = tid % NC;
        float v = 0.f;
#pragma unroll
        for (int ww = 0; ww < NWAVE; ++ww) v += part[(ww * SPB + sl) * NC + c];
        if (c == 0) v += bo[0];
        fin[sl * 16 + c] = v;
    }
    __syncthreads();
    if (tid < SPB) {
        int s = s0 + tid;
        if (s < B) {
            float f = fin[tid * 16 + 0];
            float Gf[4], Hs[10];
#pragma unroll
            for (int k = 0; k < 4; ++k) Gf[k] = fin[tid * 16 + 1 + k];
#pragma unroll
            for (int qq = 0; qq < 10; ++qq) Hs[qq] = fin[tid * 16 + 5 + qq];
            float r  = coords[s * 4 + 1];
            float th = coords[s * 4 + 2];
            float res[16];
            einstein_tail(f, Gf, Hs, r, th, res);
#pragma unroll
            for (int e = 0; e < 16; ++e) out[s * 16 + e] = res[e];
        }
    }
}

extern "C" void kernel_launch(void* const* d_in, const int* in_sizes, int n_in,
                              void* d_out, int out_size, void* d_ws, size_t ws_size,
                              hipStream_t stream) {
    const float* coords = (const float*)d_in[0];
    const float* W1 = (const float*)d_in[1];
    const float* b1 = (const float*)d_in[2];
    const float* W2 = (const float*)d_in[3];
    const float* b2 = (const float*)d_in[4];
    const float* W3 = (const float*)d_in[5];
    const float* b3 = (const float*)d_in[6];
    const float* Wo = (const float*)d_in[7];
    const float* bo = (const float*)d_in[8];
    float* out = (float*)d_out;
    const int B = in_sizes[0] / 4;
    const int nblocks = (B + SPB - 1) / SPB;

    const size_t wt_bytes = (size_t)2 * HDIM * HDIM * sizeof(_Float16);
    if (ws_size >= wt_bytes) {
        _Float16* Wt = (_Float16*)d_ws;
        pack_wt<<<32, 256, 0, stream>>>(W2, W3, Wt);
        mlp_fused<true><<<nblocks, 256, 0, stream>>>(
            coords, W1, b1, W2, b2, W3, b3, Wo, bo, Wt, out, B);
    } else {
        mlp_fused<false><<<nblocks, 256, 0, stream>>>(
            coords, W1, b1, W2, b2, W3, b3, Wo, bo, nullptr, out, B);
    }
}